// Round 12
// baseline (619.584 us; speedup 1.0000x reference)
//
#include <hip/hip_runtime.h>
#include <cstdint>

#define TPB 256
#define NBLK_A 512      // blocks in binning phase
#define BKT_SH 8        // 256 nodes per bucket; NB = ceil(N/256) (<=1024 assumed)

typedef unsigned short ushort_t;
typedef __attribute__((ext_vector_type(8)))  short    s8v;
typedef __attribute__((ext_vector_type(8)))  ushort_t u8v;
typedef __attribute__((ext_vector_type(4)))  float    f32x4;

__device__ __forceinline__ ushort_t bf16rne(float f){
  unsigned u = __float_as_uint(f);
  u += 0x7FFFu + ((u >> 16) & 1u);
  return (ushort_t)(u >> 16);
}
__device__ __forceinline__ float bf16f(ushort_t u){
  return __uint_as_float(((unsigned)u) << 16);
}
__device__ __forceinline__ float bf16lo(unsigned u){ return __uint_as_float(u << 16); }
__device__ __forceinline__ float bf16hi(unsigned u){ return __uint_as_float(u & 0xFFFF0000u); }

// ---------- A1: per-block LDS histogram of bucket ids ----------
__global__ void k_hist(const int* __restrict__ col, int E, int NB, int chunk,
                       int* __restrict__ hist /*[NB][NBLK_A]*/){
  __shared__ int lh[1024];
  int b = blockIdx.x, t = threadIdx.x;
  for (int i = t; i < NB; i += TPB) lh[i] = 0;
  __syncthreads();
  int s = b*chunk, e = min(E, s + chunk);
  for (int i = s + t; i < e; i += TPB)
    atomicAdd(&lh[col[i] >> BKT_SH], 1);
  __syncthreads();
  for (int j = t; j < NB; j += TPB) hist[(size_t)j*NBLK_A + b] = lh[j];
}

// ---------- A2a: per-bucket exclusive scan over blocks ----------
__global__ void k_bs1(int* __restrict__ hist, int* __restrict__ btot){
  __shared__ int lh[NBLK_A];
  int j = blockIdx.x, t = threadIdx.x;
  for (int b = t; b < NBLK_A; b += TPB) lh[b] = hist[(size_t)j*NBLK_A + b];
  __syncthreads();
  if (t == 0){
    int run = 0;
    for (int b = 0; b < NBLK_A; b++){ int v = lh[b]; lh[b] = run; run += v; }
    btot[j] = run;
  }
  __syncthreads();
  for (int b = t; b < NBLK_A; b += TPB) hist[(size_t)j*NBLK_A + b] = lh[b];
}

// ---------- A2b: exclusive scan over buckets ----------
__global__ void k_bs2(const int* __restrict__ btot, int NB, int* __restrict__ bbase){
  if (blockIdx.x == 0 && threadIdx.x == 0){
    int a = 0;
    for (int j = 0; j < NB; j++){ bbase[j] = a; a += btot[j]; }
    bbase[NB] = a;
  }
}

// ---------- A3: bin edges into bucket-major order (LDS cursors) ----------
__global__ void k_bin(const int* __restrict__ row, const int* __restrict__ col, int E,
                      int NB, int chunk, const int* __restrict__ hist,
                      const int* __restrict__ bbase, int2* __restrict__ binned){
  __shared__ int lcur[1024];
  int b = blockIdx.x, t = threadIdx.x;
  for (int i = t; i < NB; i += TPB) lcur[i] = 0;
  __syncthreads();
  int s = b*chunk, e = min(E, s + chunk);
  for (int i = s + t; i < e; i += TPB){
    int r = row[i], c = col[i];
    int j = c >> BKT_SH;
    int rk = atomicAdd(&lcur[j], 1);
    int pos = bbase[j] + hist[(size_t)j*NBLK_A + b] + rk;
    binned[pos] = make_int2(r, c);
  }
}

// ---------- B1: per-bucket degree count (LDS) ----------
__global__ void k_cnt(const int2* __restrict__ binned, const int* __restrict__ bbase,
                      int N, int* __restrict__ cnt){
  __shared__ int lc[256];
  int j = blockIdx.x, t = threadIdx.x;
  int base = j << BKT_SH;
  lc[t] = 0;
  __syncthreads();
  int s = bbase[j], e = bbase[j+1];
  for (int i = s + t; i < e; i += TPB)
    atomicAdd(&lc[binned[i].y - base], 1);
  __syncthreads();
  if (base + t < N) cnt[base + t] = lc[t];
}

// ---------- exclusive scan of cnt -> off, fused deg^-1/2 ----------
__global__ void k_scan1(const int* __restrict__ cnt, int N, int* __restrict__ out,
                        int* __restrict__ bsums, float* __restrict__ dis){
  __shared__ int wsum[4];
  int t = threadIdx.x;
  int base = blockIdx.x*1024 + t*4;
  int v0 = (base+0 < N) ? cnt[base+0] : 0;
  int v1 = (base+1 < N) ? cnt[base+1] : 0;
  int v2 = (base+2 < N) ? cnt[base+2] : 0;
  int v3 = (base+3 < N) ? cnt[base+3] : 0;
  if (base+0 < N) dis[base+0] = (v0 > 0) ? rsqrtf((float)v0) : 0.f;
  if (base+1 < N) dis[base+1] = (v1 > 0) ? rsqrtf((float)v1) : 0.f;
  if (base+2 < N) dis[base+2] = (v2 > 0) ? rsqrtf((float)v2) : 0.f;
  if (base+3 < N) dis[base+3] = (v3 > 0) ? rsqrtf((float)v3) : 0.f;
  int tot = v0+v1+v2+v3;
  int lane = t & 63, wid = t >> 6;
  int x = tot;
  for (int d = 1; d < 64; d <<= 1){ int y = __shfl_up(x, d); if (lane >= d) x += y; }
  if (lane == 63) wsum[wid] = x;
  __syncthreads();
  if (t == 0){ int a = 0; for (int w = 0; w < 4; w++){ int s = wsum[w]; wsum[w] = a; a += s; } bsums[blockIdx.x] = a; }
  __syncthreads();
  int run = x - tot + wsum[wid];
  if (base+0 < N) out[base+0] = run; run += v0;
  if (base+1 < N) out[base+1] = run; run += v1;
  if (base+2 < N) out[base+2] = run; run += v2;
  if (base+3 < N) out[base+3] = run;
}

__global__ void k_scan2(int* __restrict__ bsums, int nb){
  if (blockIdx.x == 0 && threadIdx.x == 0){
    int a = 0;
    for (int i = 0; i < nb; i++){ int s = bsums[i]; bsums[i] = a; a += s; }
  }
}

__global__ void k_scan3(int* __restrict__ off, const int* __restrict__ bsums, int N){
  int i = blockIdx.x*blockDim.x + threadIdx.x;
  if (i < N) off[i] += bsums[i >> 10];
}

// ---------- B2: per-bucket CSR scatter (LDS cursors) ----------
__global__ void k_scatter(const int2* __restrict__ binned, const int* __restrict__ bbase,
                          const int* __restrict__ off, int N, int* __restrict__ esrc){
  __shared__ int lcur[256];
  int j = blockIdx.x, t = threadIdx.x;
  int base = j << BKT_SH;
  lcur[t] = (base + t < N) ? off[base + t] : 0;
  __syncthreads();
  int s = bbase[j], e = bbase[j+1];
  for (int i = s + t; i < e; i += TPB){
    int2 ed = binned[i];
    int p = atomicAdd(&lcur[ed.y - base], 1);
    esrc[p] = ed.x;
  }
}

// ---------- fc1: x(N,4) -> relu(x@W1+b1), split bf16 hi/lo ----------
__global__ void k_fc1(const float* __restrict__ x, const float* __restrict__ W1,
                      const float* __restrict__ b1,
                      ushort_t* __restrict__ mhi, ushort_t* __restrict__ mlo, int N){
  __shared__ float sW[128], sb[32];
  int t = threadIdx.x;
  if (t < 128) sW[t] = W1[t];
  if (t < 32)  sb[t] = b1[t];
  __syncthreads();
  int i = blockIdx.x*TPB + t;
  if (i >= N*32) return;
  int n = i >> 5, o = i & 31;
  float4 xv = *(const float4*)&x[(size_t)n*4];
  float a = sb[o] + xv.x*sW[o] + xv.y*sW[32+o] + xv.z*sW[64+o] + xv.w*sW[96+o];
  a = fmaxf(a, 0.f);
  ushort_t h = bf16rne(a);
  mhi[i] = h;
  mlo[i] = bf16rne(a - bf16f(h));
}

// ---------- weight prep: W^T [128][K] split bf16 (ARMA: K=2F, iw then rw) ----------
__global__ void k_wprep_arma(const float* __restrict__ iw, const float* __restrict__ rw,
                             int F, ushort_t* __restrict__ Whi, ushort_t* __restrict__ Wlo){
  int idx = blockIdx.x*TPB + threadIdx.x;
  int K = 2*F;
  if (idx >= 128*K) return;
  int c = idx / K, k = idx % K;
  int ks = c >> 5, o = c & 31;
  float v = (k < F) ? iw[(ks*F + k)*32 + o] : rw[(ks*F + (k - F))*32 + o];
  ushort_t h = bf16rne(v);
  Whi[idx] = h;
  Wlo[idx] = bf16rne(v - bf16f(h));
}

__global__ void k_wprep_fc(const float* __restrict__ W, int F,
                           ushort_t* __restrict__ Whi, ushort_t* __restrict__ Wlo){
  int idx = blockIdx.x*TPB + threadIdx.x;
  if (idx >= 128*F) return;
  int c = idx / F, k = idx % F;
  float v = W[k*128 + c];
  ushort_t h = bf16rne(v);
  Whi[idx] = h;
  Wlo[idx] = bf16rne(v - bf16f(h));
}

// ---------- bf16-table gather -> split hi/lo output ----------
template<int COLS>
__global__ void k_gatherb(const unsigned* __restrict__ hb /*hi table as uint*/,
                          const int* __restrict__ off, const int* __restrict__ cnt,
                          const int* __restrict__ esrc, const float* __restrict__ dis,
                          ushort_t* __restrict__ aghi, ushort_t* __restrict__ aglo, int N){
  constexpr int LPN = COLS/8;            // lanes per node, uint4 = 8 bf16 each
  constexpr int NPB = TPB/LPN;
  constexpr int RW  = COLS/2;            // row width in uints
  int t = threadIdx.x;
  int g = t / LPN, l = t % LPN;
  int n = blockIdx.x*NPB + g;
  if (n >= N) return;
  int s = off[n], c = cnt[n];
  float acc[8];
  #pragma unroll
  for (int q = 0; q < 8; q++) acc[q] = 0.f;
  int i = 0;
  for (; i + 1 < c; i += 2){
    int s0 = esrc[s+i], s1 = esrc[s+i+1];
    float w0 = dis[s0], w1 = dis[s1];
    uint4 u0 = *(const uint4*)&hb[(size_t)s0*RW + 4*l];
    uint4 u1 = *(const uint4*)&hb[(size_t)s1*RW + 4*l];
    acc[0] += w0*bf16lo(u0.x) + w1*bf16lo(u1.x);
    acc[1] += w0*bf16hi(u0.x) + w1*bf16hi(u1.x);
    acc[2] += w0*bf16lo(u0.y) + w1*bf16lo(u1.y);
    acc[3] += w0*bf16hi(u0.y) + w1*bf16hi(u1.y);
    acc[4] += w0*bf16lo(u0.z) + w1*bf16lo(u1.z);
    acc[5] += w0*bf16hi(u0.z) + w1*bf16hi(u1.z);
    acc[6] += w0*bf16lo(u0.w) + w1*bf16lo(u1.w);
    acc[7] += w0*bf16hi(u0.w) + w1*bf16hi(u1.w);
  }
  if (i < c){
    int s0 = esrc[s+i];
    float w0 = dis[s0];
    uint4 u0 = *(const uint4*)&hb[(size_t)s0*RW + 4*l];
    acc[0] += w0*bf16lo(u0.x); acc[1] += w0*bf16hi(u0.x);
    acc[2] += w0*bf16lo(u0.y); acc[3] += w0*bf16hi(u0.y);
    acc[4] += w0*bf16lo(u0.z); acc[5] += w0*bf16hi(u0.z);
    acc[6] += w0*bf16lo(u0.w); acc[7] += w0*bf16hi(u0.w);
  }
  float wn = dis[n];
  u8v vh, vl;
  #pragma unroll
  for (int q = 0; q < 8; q++){
    float r = wn*acc[q];
    ushort_t h = bf16rne(r);
    vh[q] = h;
    vl[q] = bf16rne(r - bf16f(h));
  }
  *(u8v*)&aghi[(size_t)n*COLS + 8*l] = vh;
  *(u8v*)&aglo[(size_t)n*COLS + 8*l] = vl;
}

// ---------- MFMA GEMM: out = [G|H](N,K) @ W^T(128,K)^T, split-bf16 3-pass ----------
// Block: 256 thr = 4 waves, each wave 16 rows x 128 cols; no LDS, no barriers.
// A frag: lane l holds row (l&15), k = (l>>4)*8..+8 ; B frag from W^T[c][k], c = 16f + (l&15).
// C frag: lane l, reg q -> row (l>>4)*4+q, col 16f + (l&15)   [m89-verified]
// MODE 0: ARMA epilogue (stack-mean + relu) -> out fp32(N,32) + hi/lo bf16
// MODE 1: relu -> hi/lo bf16 (N,128)
template<int K, int TA, int MODE>
__global__ __launch_bounds__(256, 4) void k_mfma(
    const ushort_t* __restrict__ Ghi, const ushort_t* __restrict__ Glo,
    const ushort_t* __restrict__ Hhi, const ushort_t* __restrict__ Hlo,
    const ushort_t* __restrict__ Whi, const ushort_t* __restrict__ Wlo,
    const float* __restrict__ bias,
    float* __restrict__ out, ushort_t* __restrict__ ohi, ushort_t* __restrict__ olo, int N){
  constexpr int NSTEP = K/32;
  constexpr int FA = TA*32;
  constexpr int FB = K - FA;
  int t = threadIdx.x;
  int wv = t >> 6, l = t & 63;
  int lr = l & 15, kg = l >> 4;
  int nbase = blockIdx.x*64 + wv*16;
  int anode = nbase + lr;
  bool aok = anode < N;
  f32x4 acc[8];
  #pragma unroll
  for (int f = 0; f < 8; f++) acc[f] = (f32x4){0.f, 0.f, 0.f, 0.f};

  #pragma unroll
  for (int s = 0; s < NSTEP; s++){
    const ushort_t* ph = (s < TA) ? Ghi : Hhi;
    const ushort_t* pl = (s < TA) ? Glo : Hlo;
    const int F  = (s < TA) ? FA : FB;
    const int kf = ((s < TA) ? s*32 : (s - TA)*32) + kg*8;
    s8v ahi = (s8v)(short)0, alo = (s8v)(short)0;
    if (aok){
      ahi = *(const s8v*)&ph[(size_t)anode*F + kf];
      alo = *(const s8v*)&pl[(size_t)anode*F + kf];
    }
    #pragma unroll
    for (int f = 0; f < 8; f++){
      const size_t wo = (size_t)(f*16 + lr)*K + s*32 + kg*8;
      s8v bhi = *(const s8v*)&Whi[wo];
      s8v blo = *(const s8v*)&Wlo[wo];
      acc[f] = __builtin_amdgcn_mfma_f32_16x16x32_bf16(ahi, bhi, acc[f], 0, 0, 0);
      acc[f] = __builtin_amdgcn_mfma_f32_16x16x32_bf16(ahi, blo, acc[f], 0, 0, 0);
      acc[f] = __builtin_amdgcn_mfma_f32_16x16x32_bf16(alo, bhi, acc[f], 0, 0, 0);
    }
  }

  if (MODE == 0){
    #pragma unroll
    for (int q = 0; q < 4; q++){
      int node = nbase + kg*4 + q;
      if (node >= N) continue;
      float s0 = 0.f, s1 = 0.f;
      #pragma unroll
      for (int k = 0; k < 4; k++){
        s0 += fmaxf(acc[2*k][q]   + bias[k*32 + lr],      0.f);
        s1 += fmaxf(acc[2*k+1][q] + bias[k*32 + 16 + lr], 0.f);
      }
      float v0 = 0.25f*s0, v1 = 0.25f*s1;
      out[(size_t)node*32 + lr]      = v0;
      out[(size_t)node*32 + 16 + lr] = v1;
      ushort_t h0 = bf16rne(v0), h1 = bf16rne(v1);
      ohi[(size_t)node*32 + lr]      = h0;
      ohi[(size_t)node*32 + 16 + lr] = h1;
      olo[(size_t)node*32 + lr]      = bf16rne(v0 - bf16f(h0));
      olo[(size_t)node*32 + 16 + lr] = bf16rne(v1 - bf16f(h1));
    }
  } else {
    #pragma unroll
    for (int q = 0; q < 4; q++){
      int node = nbase + kg*4 + q;
      if (node >= N) continue;
      #pragma unroll
      for (int f = 0; f < 8; f++){
        float v = fmaxf(acc[f][q] + bias[f*16 + lr], 0.f);
        ushort_t h = bf16rne(v);
        ohi[(size_t)node*128 + f*16 + lr] = h;
        olo[(size_t)node*128 + f*16 + lr] = bf16rne(v - bf16f(h));
      }
    }
  }
}

// ---------- head: relu(h@W3+b3)@W4+b4 ----------
__global__ void k_head(const float* __restrict__ h,
                       const float* __restrict__ W3, const float* __restrict__ b3,
                       const float* __restrict__ W4, const float* __restrict__ b4,
                       float* __restrict__ out, int N){
  __shared__ float sW3[32*16], sb3[16], sW4[16*2], sb4[2];
  int t = threadIdx.x;
  for (int i = t; i < 512; i += TPB) sW3[i] = W3[i];
  if (t < 16) sb3[t] = b3[t];
  if (t < 32) sW4[t] = W4[t];
  if (t < 2)  sb4[t] = b4[t];
  __syncthreads();
  int n = blockIdx.x*TPB + t;
  if (n >= N) return;
  float hin[32];
  #pragma unroll
  for (int j = 0; j < 32; j++) hin[j] = h[(size_t)n*32 + j];
  float m[16];
  #pragma unroll
  for (int o = 0; o < 16; o++){
    float a = sb3[o];
    #pragma unroll
    for (int j = 0; j < 32; j++) a += hin[j]*sW3[j*16 + o];
    m[o] = fmaxf(a, 0.f);
  }
  float o0 = sb4[0], o1 = sb4[1];
  #pragma unroll
  for (int j = 0; j < 16; j++){ o0 += m[j]*sW4[j*2]; o1 += m[j]*sW4[j*2+1]; }
  out[(size_t)n*2]     = o0;
  out[(size_t)n*2 + 1] = o1;
}

extern "C" void kernel_launch(void* const* d_in, const int* in_sizes, int n_in,
                              void* d_out, int out_size, void* d_ws, size_t ws_size,
                              hipStream_t stream){
  const float* x     = (const float*)d_in[0];
  const int*   ei    = (const int*)  d_in[1];
  const float* fc1_w = (const float*)d_in[2];
  const float* fc1_b = (const float*)d_in[3];
  const float* fc2_w = (const float*)d_in[4];
  const float* fc2_b = (const float*)d_in[5];
  const float* a_iw[4] = {(const float*)d_in[6],  (const float*)d_in[9],  (const float*)d_in[12], (const float*)d_in[15]};
  const float* a_rw[4] = {(const float*)d_in[7],  (const float*)d_in[10], (const float*)d_in[13], (const float*)d_in[16]};
  const float* a_b [4] = {(const float*)d_in[8],  (const float*)d_in[11], (const float*)d_in[14], (const float*)d_in[17]};
  const float* fc3_w = (const float*)d_in[18];
  const float* fc3_b = (const float*)d_in[19];
  const float* fc4_w = (const float*)d_in[20];
  const float* fc4_b = (const float*)d_in[21];

  const int N = in_sizes[0] / 4;
  const int E = in_sizes[1] / 2;
  const int* row = ei;
  const int* col = ei + E;
  const int NB = (N + 255) >> BKT_SH;
  const int chunk = (E + NBLK_A - 1) / NBLK_A;

  char* p = (char*)d_ws;
  auto alloc = [&](size_t bytes)->void*{
    void* q = (void*)p;
    p += (bytes + 255) & ~size_t(255);
    return q;
  };
  float*    dis    = (float*)   alloc((size_t)N*4);
  int*      cnt    = (int*)     alloc((size_t)N*4);
  int*      off    = (int*)     alloc((size_t)N*4);
  const int nb     = (N + 1023) / 1024;
  int*      bsums  = (int*)     alloc((size_t)nb*4);
  int*      esrc   = (int*)     alloc((size_t)E*4);
  int2*     binned = (int2*)    alloc((size_t)E*8);
  int*      hist   = (int*)     alloc((size_t)NB*NBLK_A*4);
  int*      btot   = (int*)     alloc((size_t)NB*4);
  int*      bbase  = (int*)     alloc((size_t)(NB+1)*4);
  ushort_t* mhi    = (ushort_t*)alloc((size_t)N*32*2);
  ushort_t* mlo    = (ushort_t*)alloc((size_t)N*32*2);
  ushort_t* h1hi   = (ushort_t*)alloc((size_t)N*128*2);
  ushort_t* h1lo   = (ushort_t*)alloc((size_t)N*128*2);
  ushort_t* agHhi  = (ushort_t*)alloc((size_t)N*128*2);
  ushort_t* agHlo  = (ushort_t*)alloc((size_t)N*128*2);
  ushort_t* agShi  = (ushort_t*)alloc((size_t)N*32*2);
  ushort_t* agSlo  = (ushort_t*)alloc((size_t)N*32*2);
  float*    h2f    = (float*)   alloc((size_t)N*32*4);
  ushort_t* h2hi   = (ushort_t*)alloc((size_t)N*32*2);
  ushort_t* h2lo   = (ushort_t*)alloc((size_t)N*32*2);
  float*    h3f    = (float*)   alloc((size_t)N*32*4);
  ushort_t* h3hi   = (ushort_t*)alloc((size_t)N*32*2);
  ushort_t* h3lo   = (ushort_t*)alloc((size_t)N*32*2);
  ushort_t* WFhi   = (ushort_t*)alloc((size_t)128*32*2);
  ushort_t* WFlo   = (ushort_t*)alloc((size_t)128*32*2);
  ushort_t* W1hi   = (ushort_t*)alloc((size_t)128*256*2);
  ushort_t* W1lo   = (ushort_t*)alloc((size_t)128*256*2);
  ushort_t* WAhi[4], *WAlo[4];
  WAhi[0] = W1hi; WAlo[0] = W1lo;
  for (int L = 1; L < 4; L++){
    WAhi[L] = (ushort_t*)alloc((size_t)128*64*2);
    WAlo[L] = (ushort_t*)alloc((size_t)128*64*2);
  }

  // ---- atomic-free bucketed CSR build ----
  k_hist   <<<NBLK_A, TPB, 0, stream>>>(col, E, NB, chunk, hist);
  k_bs1    <<<NB, TPB, 0, stream>>>(hist, btot);
  k_bs2    <<<1, 1, 0, stream>>>(btot, NB, bbase);
  k_bin    <<<NBLK_A, TPB, 0, stream>>>(row, col, E, NB, chunk, hist, bbase, binned);
  k_cnt    <<<NB, TPB, 0, stream>>>(binned, bbase, N, cnt);
  k_scan1  <<<nb, TPB, 0, stream>>>(cnt, N, off, bsums, dis);
  k_scan2  <<<1, 1, 0, stream>>>(bsums, nb);
  k_scan3  <<<(N+TPB-1)/TPB, TPB, 0, stream>>>(off, bsums, N);
  k_scatter<<<NB, TPB, 0, stream>>>(binned, bbase, off, N, esrc);

  // weight prep (tiny)
  k_wprep_fc  <<<(128*32+TPB-1)/TPB,   TPB, 0, stream>>>(fc2_w, 32, WFhi, WFlo);
  k_wprep_arma<<<(128*256+TPB-1)/TPB,  TPB, 0, stream>>>(a_iw[0], a_rw[0], 128, W1hi, W1lo);
  for (int L = 1; L < 4; L++)
    k_wprep_arma<<<(128*64+TPB-1)/TPB, TPB, 0, stream>>>(a_iw[L], a_rw[L], 32, WAhi[L], WAlo[L]);

  const int gm = (N + 63) / 64;
  k_fc1<<<((size_t)N*32+TPB-1)/TPB, TPB, 0, stream>>>(x, fc1_w, fc1_b, mhi, mlo, N);
  k_mfma<32,1,1><<<gm, TPB, 0, stream>>>(mhi, mlo, mhi, mlo, WFhi, WFlo, fc2_b,
                                         nullptr, h1hi, h1lo, N);

  // ARMA 1 (fin=128): bf16 gather (hi table), split-MFMA -> h2
  k_gatherb<128><<<(N+15)/16, TPB, 0, stream>>>((const unsigned*)h1hi, off, cnt, esrc, dis, agHhi, agHlo, N);
  k_mfma<256,4,0><<<gm, TPB, 0, stream>>>(agHhi, agHlo, h1hi, h1lo, W1hi, W1lo, a_b[0],
                                          h2f, h2hi, h2lo, N);

  // ARMA 2..4 (fin=32): ping-pong (h2,*) <-> (h3,*)
  const ushort_t* hih = h2hi; const ushort_t* hil = h2lo;
  float* hof = h3f; ushort_t* hoh = h3hi; ushort_t* hol = h3lo;
  float* haltf = h2f;
  for (int L = 1; L < 4; L++){
    k_gatherb<32><<<(N+63)/64, TPB, 0, stream>>>((const unsigned*)hih, off, cnt, esrc, dis, agShi, agSlo, N);
    k_mfma<64,1,0><<<gm, TPB, 0, stream>>>(agShi, agSlo, hih, hil, WAhi[L], WAlo[L], a_b[L],
                                           hof, hoh, hol, N);
    const ushort_t* th = hih; hih = hoh; hoh = (ushort_t*)th;
    const ushort_t* tl = hil; hil = hol; hol = (ushort_t*)tl;
    float* tf = haltf; haltf = hof; hof = tf;
  }

  // L2 wrote h3*, L3 wrote h2*, L4 wrote h3* -> final fp32 in h3f
  k_head<<<(N+TPB-1)/TPB, TPB, 0, stream>>>(h3f, fc3_w, fc3_b, fc4_w, fc4_b, (float*)d_out, N);
}

// Round 14
// 484.644 us; speedup vs baseline: 1.2784x; 1.2784x over previous
//
#include <hip/hip_runtime.h>
#include <cstdint>

#define TPB 256
#define NBLK_A 512      // blocks in binning phase
#define BKT_SH 8        // 256 nodes per bucket; NB = ceil(N/256) (<=1024 assumed)

typedef unsigned short ushort_t;
typedef __attribute__((ext_vector_type(8)))  short    s8v;
typedef __attribute__((ext_vector_type(8)))  ushort_t u8v;
typedef __attribute__((ext_vector_type(4)))  float    f32x4;

__device__ __forceinline__ ushort_t bf16rne(float f){
  unsigned u = __float_as_uint(f);
  u += 0x7FFFu + ((u >> 16) & 1u);
  return (ushort_t)(u >> 16);
}
__device__ __forceinline__ float bf16f(ushort_t u){
  return __uint_as_float(((unsigned)u) << 16);
}
__device__ __forceinline__ float bf16lo(unsigned u){ return __uint_as_float(u << 16); }
__device__ __forceinline__ float bf16hi(unsigned u){ return __uint_as_float(u & 0xFFFF0000u); }

// ---------- A1: per-block LDS histogram of bucket ids ----------
__global__ void k_hist(const int* __restrict__ col, int E, int NB, int chunk,
                       int* __restrict__ hist /*[NB][NBLK_A]*/){
  __shared__ int lh[1024];
  int b = blockIdx.x, t = threadIdx.x;
  for (int i = t; i < NB; i += TPB) lh[i] = 0;
  __syncthreads();
  int s = b*chunk, e = min(E, s + chunk);
  for (int i = s + t; i < e; i += TPB)
    atomicAdd(&lh[col[i] >> BKT_SH], 1);
  __syncthreads();
  for (int j = t; j < NB; j += TPB) hist[(size_t)j*NBLK_A + b] = lh[j];
}

// ---------- A2a: per-bucket exclusive scan over blocks ----------
__global__ void k_bs1(int* __restrict__ hist, int* __restrict__ btot){
  __shared__ int lh[NBLK_A];
  int j = blockIdx.x, t = threadIdx.x;
  for (int b = t; b < NBLK_A; b += TPB) lh[b] = hist[(size_t)j*NBLK_A + b];
  __syncthreads();
  if (t == 0){
    int run = 0;
    for (int b = 0; b < NBLK_A; b++){ int v = lh[b]; lh[b] = run; run += v; }
    btot[j] = run;
  }
  __syncthreads();
  for (int b = t; b < NBLK_A; b += TPB) hist[(size_t)j*NBLK_A + b] = lh[b];
}

// ---------- A2b: exclusive scan over buckets ----------
__global__ void k_bs2(const int* __restrict__ btot, int NB, int* __restrict__ bbase){
  if (blockIdx.x == 0 && threadIdx.x == 0){
    int a = 0;
    for (int j = 0; j < NB; j++){ bbase[j] = a; a += btot[j]; }
    bbase[NB] = a;
  }
}

// ---------- A3: bin edges into bucket-major order (LDS cursors) ----------
__global__ void k_bin(const int* __restrict__ row, const int* __restrict__ col, int E,
                      int NB, int chunk, const int* __restrict__ hist,
                      const int* __restrict__ bbase, int2* __restrict__ binned){
  __shared__ int lcur[1024];
  int b = blockIdx.x, t = threadIdx.x;
  for (int i = t; i < NB; i += TPB) lcur[i] = 0;
  __syncthreads();
  int s = b*chunk, e = min(E, s + chunk);
  for (int i = s + t; i < e; i += TPB){
    int r = row[i], c = col[i];
    int j = c >> BKT_SH;
    int rk = atomicAdd(&lcur[j], 1);
    int pos = bbase[j] + hist[(size_t)j*NBLK_A + b] + rk;
    binned[pos] = make_int2(r, c);
  }
}

// ---------- B1: per-bucket degree count (LDS) ----------
__global__ void k_cnt(const int2* __restrict__ binned, const int* __restrict__ bbase,
                      int N, int* __restrict__ cnt){
  __shared__ int lc[256];
  int j = blockIdx.x, t = threadIdx.x;
  int base = j << BKT_SH;
  lc[t] = 0;
  __syncthreads();
  int s = bbase[j], e = bbase[j+1];
  for (int i = s + t; i < e; i += TPB)
    atomicAdd(&lc[binned[i].y - base], 1);
  __syncthreads();
  if (base + t < N) cnt[base + t] = lc[t];
}

// ---------- exclusive scan of cnt -> off, fused deg^-1/2 ----------
__global__ void k_scan1(const int* __restrict__ cnt, int N, int* __restrict__ out,
                        int* __restrict__ bsums, float* __restrict__ dis){
  __shared__ int wsum[4];
  int t = threadIdx.x;
  int base = blockIdx.x*1024 + t*4;
  int v0 = (base+0 < N) ? cnt[base+0] : 0;
  int v1 = (base+1 < N) ? cnt[base+1] : 0;
  int v2 = (base+2 < N) ? cnt[base+2] : 0;
  int v3 = (base+3 < N) ? cnt[base+3] : 0;
  if (base+0 < N) dis[base+0] = (v0 > 0) ? rsqrtf((float)v0) : 0.f;
  if (base+1 < N) dis[base+1] = (v1 > 0) ? rsqrtf((float)v1) : 0.f;
  if (base+2 < N) dis[base+2] = (v2 > 0) ? rsqrtf((float)v2) : 0.f;
  if (base+3 < N) dis[base+3] = (v3 > 0) ? rsqrtf((float)v3) : 0.f;
  int tot = v0+v1+v2+v3;
  int lane = t & 63, wid = t >> 6;
  int x = tot;
  for (int d = 1; d < 64; d <<= 1){ int y = __shfl_up(x, d); if (lane >= d) x += y; }
  if (lane == 63) wsum[wid] = x;
  __syncthreads();
  if (t == 0){ int a = 0; for (int w = 0; w < 4; w++){ int s = wsum[w]; wsum[w] = a; a += s; } bsums[blockIdx.x] = a; }
  __syncthreads();
  int run = x - tot + wsum[wid];
  if (base+0 < N) out[base+0] = run; run += v0;
  if (base+1 < N) out[base+1] = run; run += v1;
  if (base+2 < N) out[base+2] = run; run += v2;
  if (base+3 < N) out[base+3] = run;
}

__global__ void k_scan2(int* __restrict__ bsums, int nb){
  if (blockIdx.x == 0 && threadIdx.x == 0){
    int a = 0;
    for (int i = 0; i < nb; i++){ int s = bsums[i]; bsums[i] = a; a += s; }
  }
}

__global__ void k_scan3(int* __restrict__ off, const int* __restrict__ bsums, int N){
  int i = blockIdx.x*blockDim.x + threadIdx.x;
  if (i < N) off[i] += bsums[i >> 10];
}

// ---------- B2: per-bucket CSR scatter (LDS cursors) ----------
__global__ void k_scatter(const int2* __restrict__ binned, const int* __restrict__ bbase,
                          const int* __restrict__ off, int N, int* __restrict__ esrc){
  __shared__ int lcur[256];
  int j = blockIdx.x, t = threadIdx.x;
  int base = j << BKT_SH;
  lcur[t] = (base + t < N) ? off[base + t] : 0;
  __syncthreads();
  int s = bbase[j], e = bbase[j+1];
  for (int i = s + t; i < e; i += TPB){
    int2 ed = binned[i];
    int p = atomicAdd(&lcur[ed.y - base], 1);
    esrc[p] = ed.x;
  }
}

// ---------- fc1: x(N,4) -> relu(x@W1+b1), split bf16 hi/lo ----------
__global__ void k_fc1(const float* __restrict__ x, const float* __restrict__ W1,
                      const float* __restrict__ b1,
                      ushort_t* __restrict__ mhi, ushort_t* __restrict__ mlo, int N){
  __shared__ float sW[128], sb[32];
  int t = threadIdx.x;
  if (t < 128) sW[t] = W1[t];
  if (t < 32)  sb[t] = b1[t];
  __syncthreads();
  int i = blockIdx.x*TPB + t;
  if (i >= N*32) return;
  int n = i >> 5, o = i & 31;
  float4 xv = *(const float4*)&x[(size_t)n*4];
  float a = sb[o] + xv.x*sW[o] + xv.y*sW[32+o] + xv.z*sW[64+o] + xv.w*sW[96+o];
  a = fmaxf(a, 0.f);
  ushort_t h = bf16rne(a);
  mhi[i] = h;
  mlo[i] = bf16rne(a - bf16f(h));
}

// ---------- weight prep: W^T [128][K] split bf16 (ARMA: K=2F, iw then rw) ----------
__global__ void k_wprep_arma(const float* __restrict__ iw, const float* __restrict__ rw,
                             int F, ushort_t* __restrict__ Whi, ushort_t* __restrict__ Wlo){
  int idx = blockIdx.x*TPB + threadIdx.x;
  int K = 2*F;
  if (idx >= 128*K) return;
  int c = idx / K, k = idx % K;
  int ks = c >> 5, o = c & 31;
  float v = (k < F) ? iw[(ks*F + k)*32 + o] : rw[(ks*F + (k - F))*32 + o];
  ushort_t h = bf16rne(v);
  Whi[idx] = h;
  Wlo[idx] = bf16rne(v - bf16f(h));
}

__global__ void k_wprep_fc(const float* __restrict__ W, int F,
                           ushort_t* __restrict__ Whi, ushort_t* __restrict__ Wlo){
  int idx = blockIdx.x*TPB + threadIdx.x;
  if (idx >= 128*F) return;
  int c = idx / F, k = idx % F;
  float v = W[k*128 + c];
  ushort_t h = bf16rne(v);
  Whi[idx] = h;
  Wlo[idx] = bf16rne(v - bf16f(h));
}

// ---------- bf16-table gather -> split hi/lo output ----------
template<int COLS>
__global__ void k_gatherb(const unsigned* __restrict__ hb /*hi table as uint*/,
                          const int* __restrict__ off, const int* __restrict__ cnt,
                          const int* __restrict__ esrc, const float* __restrict__ dis,
                          ushort_t* __restrict__ aghi, ushort_t* __restrict__ aglo, int N){
  constexpr int LPN = COLS/8;            // lanes per node, uint4 = 8 bf16 each
  constexpr int NPB = TPB/LPN;
  constexpr int RW  = COLS/2;            // row width in uints
  int t = threadIdx.x;
  int g = t / LPN, l = t % LPN;
  int n = blockIdx.x*NPB + g;
  if (n >= N) return;
  int s = off[n], c = cnt[n];
  float acc[8];
  #pragma unroll
  for (int q = 0; q < 8; q++) acc[q] = 0.f;
  int i = 0;
  for (; i + 1 < c; i += 2){
    int s0 = esrc[s+i], s1 = esrc[s+i+1];
    float w0 = dis[s0], w1 = dis[s1];
    uint4 u0 = *(const uint4*)&hb[(size_t)s0*RW + 4*l];
    uint4 u1 = *(const uint4*)&hb[(size_t)s1*RW + 4*l];
    acc[0] += w0*bf16lo(u0.x) + w1*bf16lo(u1.x);
    acc[1] += w0*bf16hi(u0.x) + w1*bf16hi(u1.x);
    acc[2] += w0*bf16lo(u0.y) + w1*bf16lo(u1.y);
    acc[3] += w0*bf16hi(u0.y) + w1*bf16hi(u1.y);
    acc[4] += w0*bf16lo(u0.z) + w1*bf16lo(u1.z);
    acc[5] += w0*bf16hi(u0.z) + w1*bf16hi(u1.z);
    acc[6] += w0*bf16lo(u0.w) + w1*bf16lo(u1.w);
    acc[7] += w0*bf16hi(u0.w) + w1*bf16hi(u1.w);
  }
  if (i < c){
    int s0 = esrc[s+i];
    float w0 = dis[s0];
    uint4 u0 = *(const uint4*)&hb[(size_t)s0*RW + 4*l];
    acc[0] += w0*bf16lo(u0.x); acc[1] += w0*bf16hi(u0.x);
    acc[2] += w0*bf16lo(u0.y); acc[3] += w0*bf16hi(u0.y);
    acc[4] += w0*bf16lo(u0.z); acc[5] += w0*bf16hi(u0.z);
    acc[6] += w0*bf16lo(u0.w); acc[7] += w0*bf16hi(u0.w);
  }
  float wn = dis[n];
  u8v vh, vl;
  #pragma unroll
  for (int q = 0; q < 8; q++){
    float r = wn*acc[q];
    ushort_t h = bf16rne(r);
    vh[q] = h;
    vl[q] = bf16rne(r - bf16f(h));
  }
  *(u8v*)&aghi[(size_t)n*COLS + 8*l] = vh;
  *(u8v*)&aglo[(size_t)n*COLS + 8*l] = vl;
}

// ---------- MFMA GEMM with LDS-staged operands, split-bf16 3-pass ----------
// Block: 256 thr = 4 waves; tile = 64 nodes x 128 cols; per k-step stage
// A-slice [64][32] hi+lo (8 KB) + W-slice [128][32] hi+lo (16 KB) into LDS.
// Fragment reads are ds_read_b128; layouts identical to the r12-verified kernel.
// MODE 0: ARMA epilogue (stack-mean + relu) -> out fp32(N,32) + hi/lo bf16
// MODE 1: relu -> hi/lo bf16 (N,128)
template<int K, int TA, int MODE>
__global__ __launch_bounds__(256, 2) void k_mfma(
    const ushort_t* __restrict__ Ghi, const ushort_t* __restrict__ Glo,
    const ushort_t* __restrict__ Hhi, const ushort_t* __restrict__ Hlo,
    const ushort_t* __restrict__ Whi, const ushort_t* __restrict__ Wlo,
    const float* __restrict__ bias,
    float* __restrict__ out, ushort_t* __restrict__ ohi, ushort_t* __restrict__ olo, int N){
  constexpr int NSTEP = K/32;
  constexpr int FA = TA*32;
  constexpr int FB = K - FA;
  __shared__ ushort_t sAh[64*32], sAl[64*32];
  __shared__ ushort_t sWh[128*32], sWl[128*32];
  int t = threadIdx.x;
  int wv = t >> 6, l = t & 63;
  int lr = l & 15, kg = l >> 4;
  int nbase = blockIdx.x*64 + wv*16;
  f32x4 acc[8];
  #pragma unroll
  for (int f = 0; f < 8; f++) acc[f] = (f32x4){0.f, 0.f, 0.f, 0.f};

  #pragma unroll
  for (int s = 0; s < NSTEP; s++){
    const ushort_t* ph = (s < TA) ? Ghi : Hhi;
    const ushort_t* pl = (s < TA) ? Glo : Hlo;
    const int F  = (s < TA) ? FA : FB;
    const int kb = (s < TA) ? s*32 : (s - TA)*32;
    if (s > 0) __syncthreads();
    // stage A slice: thread t -> node t>>2 (0..63), chunk t&3 (8 bf16 each)
    {
      int n = t >> 2, jj = t & 3;
      int node = blockIdx.x*64 + n;
      u8v vh = (u8v)(ushort_t)0, vl = (u8v)(ushort_t)0;
      if (node < N){
        vh = *(const u8v*)&ph[(size_t)node*F + kb + jj*8];
        vl = *(const u8v*)&pl[(size_t)node*F + kb + jj*8];
      }
      *(u8v*)&sAh[n*32 + jj*8] = vh;
      *(u8v*)&sAl[n*32 + jj*8] = vl;
    }
    // stage W slice: 128 cols x 32 k
    #pragma unroll
    for (int j = 0; j < 2; j++){
      int q = t + j*256;
      int c = q >> 2, jj = q & 3;
      *(u8v*)&sWh[c*32 + jj*8] = *(const u8v*)&Whi[(size_t)c*K + s*32 + jj*8];
      *(u8v*)&sWl[c*32 + jj*8] = *(const u8v*)&Wlo[(size_t)c*K + s*32 + jj*8];
    }
    __syncthreads();
    s8v ahi = *(const s8v*)&sAh[(wv*16 + lr)*32 + kg*8];
    s8v alo = *(const s8v*)&sAl[(wv*16 + lr)*32 + kg*8];
    #pragma unroll
    for (int f = 0; f < 8; f++){
      s8v bhi = *(const s8v*)&sWh[(f*16 + lr)*32 + kg*8];
      s8v blo = *(const s8v*)&sWl[(f*16 + lr)*32 + kg*8];
      acc[f] = __builtin_amdgcn_mfma_f32_16x16x32_bf16(ahi, bhi, acc[f], 0, 0, 0);
      acc[f] = __builtin_amdgcn_mfma_f32_16x16x32_bf16(ahi, blo, acc[f], 0, 0, 0);
      acc[f] = __builtin_amdgcn_mfma_f32_16x16x32_bf16(alo, bhi, acc[f], 0, 0, 0);
    }
  }

  if (MODE == 0){
    #pragma unroll
    for (int q = 0; q < 4; q++){
      int node = nbase + kg*4 + q;
      if (node >= N) continue;
      float s0 = 0.f, s1 = 0.f;
      #pragma unroll
      for (int k = 0; k < 4; k++){
        s0 += fmaxf(acc[2*k][q]   + bias[k*32 + lr],      0.f);
        s1 += fmaxf(acc[2*k+1][q] + bias[k*32 + 16 + lr], 0.f);
      }
      float v0 = 0.25f*s0, v1 = 0.25f*s1;
      out[(size_t)node*32 + lr]      = v0;
      out[(size_t)node*32 + 16 + lr] = v1;
      ushort_t h0 = bf16rne(v0), h1 = bf16rne(v1);
      ohi[(size_t)node*32 + lr]      = h0;
      ohi[(size_t)node*32 + 16 + lr] = h1;
      olo[(size_t)node*32 + lr]      = bf16rne(v0 - bf16f(h0));
      olo[(size_t)node*32 + 16 + lr] = bf16rne(v1 - bf16f(h1));
    }
  } else {
    #pragma unroll
    for (int q = 0; q < 4; q++){
      int node = nbase + kg*4 + q;
      if (node >= N) continue;
      #pragma unroll
      for (int f = 0; f < 8; f++){
        float v = fmaxf(acc[f][q] + bias[f*16 + lr], 0.f);
        ushort_t h = bf16rne(v);
        ohi[(size_t)node*128 + f*16 + lr] = h;
        olo[(size_t)node*128 + f*16 + lr] = bf16rne(v - bf16f(h));
      }
    }
  }
}

// ---------- head: relu(h@W3+b3)@W4+b4 ----------
__global__ void k_head(const float* __restrict__ h,
                       const float* __restrict__ W3, const float* __restrict__ b3,
                       const float* __restrict__ W4, const float* __restrict__ b4,
                       float* __restrict__ out, int N){
  __shared__ float sW3[32*16], sb3[16], sW4[16*2], sb4[2];
  int t = threadIdx.x;
  for (int i = t; i < 512; i += TPB) sW3[i] = W3[i];
  if (t < 16) sb3[t] = b3[t];
  if (t < 32) sW4[t] = W4[t];
  if (t < 2)  sb4[t] = b4[t];
  __syncthreads();
  int n = blockIdx.x*TPB + t;
  if (n >= N) return;
  float hin[32];
  #pragma unroll
  for (int j = 0; j < 32; j++) hin[j] = h[(size_t)n*32 + j];
  float m[16];
  #pragma unroll
  for (int o = 0; o < 16; o++){
    float a = sb3[o];
    #pragma unroll
    for (int j = 0; j < 32; j++) a += hin[j]*sW3[j*16 + o];
    m[o] = fmaxf(a, 0.f);
  }
  float o0 = sb4[0], o1 = sb4[1];
  #pragma unroll
  for (int j = 0; j < 16; j++){ o0 += m[j]*sW4[j*2]; o1 += m[j]*sW4[j*2+1]; }
  out[(size_t)n*2]     = o0;
  out[(size_t)n*2 + 1] = o1;
}

extern "C" void kernel_launch(void* const* d_in, const int* in_sizes, int n_in,
                              void* d_out, int out_size, void* d_ws, size_t ws_size,
                              hipStream_t stream){
  const float* x     = (const float*)d_in[0];
  const int*   ei    = (const int*)  d_in[1];
  const float* fc1_w = (const float*)d_in[2];
  const float* fc1_b = (const float*)d_in[3];
  const float* fc2_w = (const float*)d_in[4];
  const float* fc2_b = (const float*)d_in[5];
  const float* a_iw[4] = {(const float*)d_in[6],  (const float*)d_in[9],  (const float*)d_in[12], (const float*)d_in[15]};
  const float* a_rw[4] = {(const float*)d_in[7],  (const float*)d_in[10], (const float*)d_in[13], (const float*)d_in[16]};
  const float* a_b [4] = {(const float*)d_in[8],  (const float*)d_in[11], (const float*)d_in[14], (const float*)d_in[17]};
  const float* fc3_w = (const float*)d_in[18];
  const float* fc3_b = (const float*)d_in[19];
  const float* fc4_w = (const float*)d_in[20];
  const float* fc4_b = (const float*)d_in[21];

  const int N = in_sizes[0] / 4;
  const int E = in_sizes[1] / 2;
  const int* row = ei;
  const int* col = ei + E;
  const int NB = (N + 255) >> BKT_SH;
  const int chunk = (E + NBLK_A - 1) / NBLK_A;

  char* p = (char*)d_ws;
  auto alloc = [&](size_t bytes)->void*{
    void* q = (void*)p;
    p += (bytes + 255) & ~size_t(255);
    return q;
  };
  float*    dis    = (float*)   alloc((size_t)N*4);
  int*      cnt    = (int*)     alloc((size_t)N*4);
  int*      off    = (int*)     alloc((size_t)N*4);
  const int nb     = (N + 1023) / 1024;
  int*      bsums  = (int*)     alloc((size_t)nb*4);
  int*      esrc   = (int*)     alloc((size_t)E*4);
  int2*     binned = (int2*)    alloc((size_t)E*8);
  int*      hist   = (int*)     alloc((size_t)NB*NBLK_A*4);
  int*      btot   = (int*)     alloc((size_t)NB*4);
  int*      bbase  = (int*)     alloc((size_t)(NB+1)*4);
  ushort_t* mhi    = (ushort_t*)alloc((size_t)N*32*2);
  ushort_t* mlo    = (ushort_t*)alloc((size_t)N*32*2);
  ushort_t* h1hi   = (ushort_t*)alloc((size_t)N*128*2);
  ushort_t* h1lo   = (ushort_t*)alloc((size_t)N*128*2);
  ushort_t* agHhi  = (ushort_t*)alloc((size_t)N*128*2);
  ushort_t* agHlo  = (ushort_t*)alloc((size_t)N*128*2);
  ushort_t* agShi  = (ushort_t*)alloc((size_t)N*32*2);
  ushort_t* agSlo  = (ushort_t*)alloc((size_t)N*32*2);
  float*    h2f    = (float*)   alloc((size_t)N*32*4);
  ushort_t* h2hi   = (ushort_t*)alloc((size_t)N*32*2);
  ushort_t* h2lo   = (ushort_t*)alloc((size_t)N*32*2);
  float*    h3f    = (float*)   alloc((size_t)N*32*4);
  ushort_t* h3hi   = (ushort_t*)alloc((size_t)N*32*2);
  ushort_t* h3lo   = (ushort_t*)alloc((size_t)N*32*2);
  ushort_t* WFhi   = (ushort_t*)alloc((size_t)128*32*2);
  ushort_t* WFlo   = (ushort_t*)alloc((size_t)128*32*2);
  ushort_t* W1hi   = (ushort_t*)alloc((size_t)128*256*2);
  ushort_t* W1lo   = (ushort_t*)alloc((size_t)128*256*2);
  ushort_t* WAhi[4], *WAlo[4];
  WAhi[0] = W1hi; WAlo[0] = W1lo;
  for (int L = 1; L < 4; L++){
    WAhi[L] = (ushort_t*)alloc((size_t)128*64*2);
    WAlo[L] = (ushort_t*)alloc((size_t)128*64*2);
  }

  // ---- atomic-free bucketed CSR build ----
  k_hist   <<<NBLK_A, TPB, 0, stream>>>(col, E, NB, chunk, hist);
  k_bs1    <<<NB, TPB, 0, stream>>>(hist, btot);
  k_bs2    <<<1, 1, 0, stream>>>(btot, NB, bbase);
  k_bin    <<<NBLK_A, TPB, 0, stream>>>(row, col, E, NB, chunk, hist, bbase, binned);
  k_cnt    <<<NB, TPB, 0, stream>>>(binned, bbase, N, cnt);
  k_scan1  <<<nb, TPB, 0, stream>>>(cnt, N, off, bsums, dis);
  k_scan2  <<<1, 1, 0, stream>>>(bsums, nb);
  k_scan3  <<<(N+TPB-1)/TPB, TPB, 0, stream>>>(off, bsums, N);
  k_scatter<<<NB, TPB, 0, stream>>>(binned, bbase, off, N, esrc);

  // weight prep (tiny)
  k_wprep_fc  <<<(128*32+TPB-1)/TPB,   TPB, 0, stream>>>(fc2_w, 32, WFhi, WFlo);
  k_wprep_arma<<<(128*256+TPB-1)/TPB,  TPB, 0, stream>>>(a_iw[0], a_rw[0], 128, W1hi, W1lo);
  for (int L = 1; L < 4; L++)
    k_wprep_arma<<<(128*64+TPB-1)/TPB, TPB, 0, stream>>>(a_iw[L], a_rw[L], 32, WAhi[L], WAlo[L]);

  const int gm = (N + 63) / 64;
  k_fc1<<<((size_t)N*32+TPB-1)/TPB, TPB, 0, stream>>>(x, fc1_w, fc1_b, mhi, mlo, N);
  k_mfma<32,1,1><<<gm, TPB, 0, stream>>>(mhi, mlo, mhi, mlo, WFhi, WFlo, fc2_b,
                                         nullptr, h1hi, h1lo, N);

  // ARMA 1 (fin=128): bf16 gather (hi table), split-MFMA -> h2
  k_gatherb<128><<<(N+15)/16, TPB, 0, stream>>>((const unsigned*)h1hi, off, cnt, esrc, dis, agHhi, agHlo, N);
  k_mfma<256,4,0><<<gm, TPB, 0, stream>>>(agHhi, agHlo, h1hi, h1lo, W1hi, W1lo, a_b[0],
                                          h2f, h2hi, h2lo, N);

  // ARMA 2..4 (fin=32): ping-pong (h2,*) <-> (h3,*)
  const ushort_t* hih = h2hi; const ushort_t* hil = h2lo;
  float* hof = h3f; ushort_t* hoh = h3hi; ushort_t* hol = h3lo;
  float* haltf = h2f;
  for (int L = 1; L < 4; L++){
    k_gatherb<32><<<(N+63)/64, TPB, 0, stream>>>((const unsigned*)hih, off, cnt, esrc, dis, agShi, agSlo, N);
    k_mfma<64,1,0><<<gm, TPB, 0, stream>>>(agShi, agSlo, hih, hil, WAhi[L], WAlo[L], a_b[L],
                                           hof, hoh, hol, N);
    const ushort_t* th = hih; hih = hoh; hoh = (ushort_t*)th;
    const ushort_t* tl = hil; hil = hol; hol = (ushort_t*)tl;
    float* tf = haltf; haltf = hof; hof = tf;
  }

  // L2 wrote h3*, L3 wrote h2*, L4 wrote h3* -> final fp32 in h3f
  k_head<<<(N+TPB-1)/TPB, TPB, 0, stream>>>(h3f, fc3_w, fc3_b, fc4_w, fc4_b, (float*)d_out, N);
}

// Round 15
// 449.163 us; speedup vs baseline: 1.3794x; 1.0790x over previous
//
#include <hip/hip_runtime.h>
#include <cstdint>

#define TPB 256
#define NBLK_A 512      // blocks in binning phase
#define BKT_SH 8        // 256 nodes per bucket; NB = ceil(N/256) (<=1024 assumed)

typedef unsigned short ushort_t;
typedef __attribute__((ext_vector_type(8)))  short    s8v;
typedef __attribute__((ext_vector_type(8)))  ushort_t u8v;
typedef __attribute__((ext_vector_type(4)))  float    f32x4;

__device__ __forceinline__ ushort_t bf16rne(float f){
  unsigned u = __float_as_uint(f);
  u += 0x7FFFu + ((u >> 16) & 1u);
  return (ushort_t)(u >> 16);
}
__device__ __forceinline__ float bf16f(ushort_t u){
  return __uint_as_float(((unsigned)u) << 16);
}
__device__ __forceinline__ float bf16lo(unsigned u){ return __uint_as_float(u << 16); }
__device__ __forceinline__ float bf16hi(unsigned u){ return __uint_as_float(u & 0xFFFF0000u); }

// ---------- A1: per-block LDS histogram of bucket ids ----------
__global__ void k_hist(const int* __restrict__ col, int E, int NB, int chunk,
                       int* __restrict__ hist /*[NB][NBLK_A]*/){
  __shared__ int lh[1024];
  int b = blockIdx.x, t = threadIdx.x;
  for (int i = t; i < NB; i += TPB) lh[i] = 0;
  __syncthreads();
  int s = b*chunk, e = min(E, s + chunk);
  for (int i = s + t; i < e; i += TPB)
    atomicAdd(&lh[col[i] >> BKT_SH], 1);
  __syncthreads();
  for (int j = t; j < NB; j += TPB) hist[(size_t)j*NBLK_A + b] = lh[j];
}

// ---------- A2a: per-bucket exclusive scan over blocks ----------
__global__ void k_bs1(int* __restrict__ hist, int* __restrict__ btot){
  __shared__ int lh[NBLK_A];
  int j = blockIdx.x, t = threadIdx.x;
  for (int b = t; b < NBLK_A; b += TPB) lh[b] = hist[(size_t)j*NBLK_A + b];
  __syncthreads();
  if (t == 0){
    int run = 0;
    for (int b = 0; b < NBLK_A; b++){ int v = lh[b]; lh[b] = run; run += v; }
    btot[j] = run;
  }
  __syncthreads();
  for (int b = t; b < NBLK_A; b += TPB) hist[(size_t)j*NBLK_A + b] = lh[b];
}

// ---------- A2b: exclusive scan over buckets ----------
__global__ void k_bs2(const int* __restrict__ btot, int NB, int* __restrict__ bbase){
  if (blockIdx.x == 0 && threadIdx.x == 0){
    int a = 0;
    for (int j = 0; j < NB; j++){ bbase[j] = a; a += btot[j]; }
    bbase[NB] = a;
  }
}

// ---------- A3: bin edges into bucket-major order (LDS cursors) ----------
__global__ void k_bin(const int* __restrict__ row, const int* __restrict__ col, int E,
                      int NB, int chunk, const int* __restrict__ hist,
                      const int* __restrict__ bbase, int2* __restrict__ binned){
  __shared__ int lcur[1024];
  int b = blockIdx.x, t = threadIdx.x;
  for (int i = t; i < NB; i += TPB) lcur[i] = 0;
  __syncthreads();
  int s = b*chunk, e = min(E, s + chunk);
  for (int i = s + t; i < e; i += TPB){
    int r = row[i], c = col[i];
    int j = c >> BKT_SH;
    int rk = atomicAdd(&lcur[j], 1);
    int pos = bbase[j] + hist[(size_t)j*NBLK_A + b] + rk;
    binned[pos] = make_int2(r, c);
  }
}

// ---------- B1: per-bucket degree count (LDS) ----------
__global__ void k_cnt(const int2* __restrict__ binned, const int* __restrict__ bbase,
                      int N, int* __restrict__ cnt){
  __shared__ int lc[256];
  int j = blockIdx.x, t = threadIdx.x;
  int base = j << BKT_SH;
  lc[t] = 0;
  __syncthreads();
  int s = bbase[j], e = bbase[j+1];
  for (int i = s + t; i < e; i += TPB)
    atomicAdd(&lc[binned[i].y - base], 1);
  __syncthreads();
  if (base + t < N) cnt[base + t] = lc[t];
}

// ---------- exclusive scan of cnt -> off, fused deg^-1/2 ----------
__global__ void k_scan1(const int* __restrict__ cnt, int N, int* __restrict__ out,
                        int* __restrict__ bsums, float* __restrict__ dis){
  __shared__ int wsum[4];
  int t = threadIdx.x;
  int base = blockIdx.x*1024 + t*4;
  int v0 = (base+0 < N) ? cnt[base+0] : 0;
  int v1 = (base+1 < N) ? cnt[base+1] : 0;
  int v2 = (base+2 < N) ? cnt[base+2] : 0;
  int v3 = (base+3 < N) ? cnt[base+3] : 0;
  if (base+0 < N) dis[base+0] = (v0 > 0) ? rsqrtf((float)v0) : 0.f;
  if (base+1 < N) dis[base+1] = (v1 > 0) ? rsqrtf((float)v1) : 0.f;
  if (base+2 < N) dis[base+2] = (v2 > 0) ? rsqrtf((float)v2) : 0.f;
  if (base+3 < N) dis[base+3] = (v3 > 0) ? rsqrtf((float)v3) : 0.f;
  int tot = v0+v1+v2+v3;
  int lane = t & 63, wid = t >> 6;
  int x = tot;
  for (int d = 1; d < 64; d <<= 1){ int y = __shfl_up(x, d); if (lane >= d) x += y; }
  if (lane == 63) wsum[wid] = x;
  __syncthreads();
  if (t == 0){ int a = 0; for (int w = 0; w < 4; w++){ int s = wsum[w]; wsum[w] = a; a += s; } bsums[blockIdx.x] = a; }
  __syncthreads();
  int run = x - tot + wsum[wid];
  if (base+0 < N) out[base+0] = run; run += v0;
  if (base+1 < N) out[base+1] = run; run += v1;
  if (base+2 < N) out[base+2] = run; run += v2;
  if (base+3 < N) out[base+3] = run;
}

__global__ void k_scan2(int* __restrict__ bsums, int nb){
  if (blockIdx.x == 0 && threadIdx.x == 0){
    int a = 0;
    for (int i = 0; i < nb; i++){ int s = bsums[i]; bsums[i] = a; a += s; }
  }
}

__global__ void k_scan3(int* __restrict__ off, const int* __restrict__ bsums, int N){
  int i = blockIdx.x*blockDim.x + threadIdx.x;
  if (i < N) off[i] += bsums[i >> 10];
}

// ---------- B2: per-bucket CSR scatter (LDS cursors) ----------
__global__ void k_scatter(const int2* __restrict__ binned, const int* __restrict__ bbase,
                          const int* __restrict__ off, int N, int* __restrict__ esrc){
  __shared__ int lcur[256];
  int j = blockIdx.x, t = threadIdx.x;
  int base = j << BKT_SH;
  lcur[t] = (base + t < N) ? off[base + t] : 0;
  __syncthreads();
  int s = bbase[j], e = bbase[j+1];
  for (int i = s + t; i < e; i += TPB){
    int2 ed = binned[i];
    int p = atomicAdd(&lcur[ed.y - base], 1);
    esrc[p] = ed.x;
  }
}

// ---------- fc1: x(N,4) -> relu(x@W1+b1), split bf16 hi/lo ----------
__global__ void k_fc1(const float* __restrict__ x, const float* __restrict__ W1,
                      const float* __restrict__ b1,
                      ushort_t* __restrict__ mhi, ushort_t* __restrict__ mlo, int N){
  __shared__ float sW[128], sb[32];
  int t = threadIdx.x;
  if (t < 128) sW[t] = W1[t];
  if (t < 32)  sb[t] = b1[t];
  __syncthreads();
  int i = blockIdx.x*TPB + t;
  if (i >= N*32) return;
  int n = i >> 5, o = i & 31;
  float4 xv = *(const float4*)&x[(size_t)n*4];
  float a = sb[o] + xv.x*sW[o] + xv.y*sW[32+o] + xv.z*sW[64+o] + xv.w*sW[96+o];
  a = fmaxf(a, 0.f);
  ushort_t h = bf16rne(a);
  mhi[i] = h;
  mlo[i] = bf16rne(a - bf16f(h));
}

// ---------- weight prep: W^T [128][K] split bf16 (ARMA: K=2F, iw then rw) ----------
__global__ void k_wprep_arma(const float* __restrict__ iw, const float* __restrict__ rw,
                             int F, ushort_t* __restrict__ Whi, ushort_t* __restrict__ Wlo){
  int idx = blockIdx.x*TPB + threadIdx.x;
  int K = 2*F;
  if (idx >= 128*K) return;
  int c = idx / K, k = idx % K;
  int ks = c >> 5, o = c & 31;
  float v = (k < F) ? iw[(ks*F + k)*32 + o] : rw[(ks*F + (k - F))*32 + o];
  ushort_t h = bf16rne(v);
  Whi[idx] = h;
  Wlo[idx] = bf16rne(v - bf16f(h));
}

__global__ void k_wprep_fc(const float* __restrict__ W, int F,
                           ushort_t* __restrict__ Whi, ushort_t* __restrict__ Wlo){
  int idx = blockIdx.x*TPB + threadIdx.x;
  if (idx >= 128*F) return;
  int c = idx / F, k = idx % F;
  float v = W[k*128 + c];
  ushort_t h = bf16rne(v);
  Whi[idx] = h;
  Wlo[idx] = bf16rne(v - bf16f(h));
}

// ---------- bf16-table gather, ILP-4, hi-only output ----------
template<int COLS>
__global__ void k_gatherb(const unsigned* __restrict__ hb /*hi table as uint*/,
                          const int* __restrict__ off, const int* __restrict__ cnt,
                          const int* __restrict__ esrc, const float* __restrict__ dis,
                          ushort_t* __restrict__ aghi, int N){
  constexpr int LPN = COLS/8;            // lanes per node, uint4 = 8 bf16 each
  constexpr int NPB = TPB/LPN;
  constexpr int RW  = COLS/2;            // row width in uints
  int t = threadIdx.x;
  int g = t / LPN, l = t % LPN;
  int n = blockIdx.x*NPB + g;
  if (n >= N) return;
  int s = off[n], c = cnt[n];
  float accA[8], accB[8];
  #pragma unroll
  for (int q = 0; q < 8; q++){ accA[q] = 0.f; accB[q] = 0.f; }
  int i = 0;
  for (; i + 3 < c; i += 4){
    int s0 = esrc[s+i],   s1 = esrc[s+i+1];
    int s2 = esrc[s+i+2], s3 = esrc[s+i+3];
    float w0 = dis[s0], w1 = dis[s1], w2 = dis[s2], w3 = dis[s3];
    uint4 u0 = *(const uint4*)&hb[(size_t)s0*RW + 4*l];
    uint4 u1 = *(const uint4*)&hb[(size_t)s1*RW + 4*l];
    uint4 u2 = *(const uint4*)&hb[(size_t)s2*RW + 4*l];
    uint4 u3 = *(const uint4*)&hb[(size_t)s3*RW + 4*l];
    accA[0] += w0*bf16lo(u0.x) + w1*bf16lo(u1.x);
    accA[1] += w0*bf16hi(u0.x) + w1*bf16hi(u1.x);
    accA[2] += w0*bf16lo(u0.y) + w1*bf16lo(u1.y);
    accA[3] += w0*bf16hi(u0.y) + w1*bf16hi(u1.y);
    accA[4] += w0*bf16lo(u0.z) + w1*bf16lo(u1.z);
    accA[5] += w0*bf16hi(u0.z) + w1*bf16hi(u1.z);
    accA[6] += w0*bf16lo(u0.w) + w1*bf16lo(u1.w);
    accA[7] += w0*bf16hi(u0.w) + w1*bf16hi(u1.w);
    accB[0] += w2*bf16lo(u2.x) + w3*bf16lo(u3.x);
    accB[1] += w2*bf16hi(u2.x) + w3*bf16hi(u3.x);
    accB[2] += w2*bf16lo(u2.y) + w3*bf16lo(u3.y);
    accB[3] += w2*bf16hi(u2.y) + w3*bf16hi(u3.y);
    accB[4] += w2*bf16lo(u2.z) + w3*bf16lo(u3.z);
    accB[5] += w2*bf16hi(u2.z) + w3*bf16hi(u3.z);
    accB[6] += w2*bf16lo(u2.w) + w3*bf16lo(u3.w);
    accB[7] += w2*bf16hi(u2.w) + w3*bf16hi(u3.w);
  }
  for (; i < c; i++){
    int s0 = esrc[s+i];
    float w0 = dis[s0];
    uint4 u0 = *(const uint4*)&hb[(size_t)s0*RW + 4*l];
    accA[0] += w0*bf16lo(u0.x); accA[1] += w0*bf16hi(u0.x);
    accA[2] += w0*bf16lo(u0.y); accA[3] += w0*bf16hi(u0.y);
    accA[4] += w0*bf16lo(u0.z); accA[5] += w0*bf16hi(u0.z);
    accA[6] += w0*bf16lo(u0.w); accA[7] += w0*bf16hi(u0.w);
  }
  float wn = dis[n];
  u8v vh;
  #pragma unroll
  for (int q = 0; q < 8; q++)
    vh[q] = bf16rne(wn*(accA[q] + accB[q]));
  *(u8v*)&aghi[(size_t)n*COLS + 8*l] = vh;
}

// ---------- MFMA GEMM with LDS-staged operands ----------
// G-steps (s<TA): A has no lo (GLO=0 -> 2 MFMA passes); H-steps: 3 passes.
// MODE 0: ARMA epilogue (stack-mean + relu) -> out fp32(N,32) + hi/lo bf16
// MODE 1: relu -> hi/lo bf16 (N,128)
template<int K, int TA, int MODE, int GLO>
__global__ __launch_bounds__(256, 2) void k_mfma(
    const ushort_t* __restrict__ Ghi, const ushort_t* __restrict__ Glo,
    const ushort_t* __restrict__ Hhi, const ushort_t* __restrict__ Hlo,
    const ushort_t* __restrict__ Whi, const ushort_t* __restrict__ Wlo,
    const float* __restrict__ bias,
    float* __restrict__ out, ushort_t* __restrict__ ohi, ushort_t* __restrict__ olo, int N){
  constexpr int NSTEP = K/32;
  constexpr int FA = TA*32;
  constexpr int FB = K - FA;
  __shared__ ushort_t sAh[64*32], sAl[64*32];
  __shared__ ushort_t sWh[128*32], sWl[128*32];
  int t = threadIdx.x;
  int wv = t >> 6, l = t & 63;
  int lr = l & 15, kg = l >> 4;
  int nbase = blockIdx.x*64 + wv*16;
  f32x4 acc[8];
  #pragma unroll
  for (int f = 0; f < 8; f++) acc[f] = (f32x4){0.f, 0.f, 0.f, 0.f};

  #pragma unroll
  for (int s = 0; s < NSTEP; s++){
    const bool isG = (s < TA);
    const bool hasLo = (!isG) || (GLO != 0);
    const ushort_t* ph = isG ? Ghi : Hhi;
    const ushort_t* pl = isG ? Glo : Hlo;
    const int F  = isG ? FA : FB;
    const int kb = isG ? s*32 : (s - TA)*32;
    if (s > 0) __syncthreads();
    // stage A slice: thread t -> node t>>2 (0..63), chunk t&3 (8 bf16 each)
    {
      int n = t >> 2, jj = t & 3;
      int node = blockIdx.x*64 + n;
      u8v vh = (u8v)(ushort_t)0;
      if (node < N) vh = *(const u8v*)&ph[(size_t)node*F + kb + jj*8];
      *(u8v*)&sAh[n*32 + jj*8] = vh;
      if (hasLo){
        u8v vl = (u8v)(ushort_t)0;
        if (node < N) vl = *(const u8v*)&pl[(size_t)node*F + kb + jj*8];
        *(u8v*)&sAl[n*32 + jj*8] = vl;
      }
    }
    // stage W slice: 128 cols x 32 k
    #pragma unroll
    for (int j = 0; j < 2; j++){
      int q = t + j*256;
      int c = q >> 2, jj = q & 3;
      *(u8v*)&sWh[c*32 + jj*8] = *(const u8v*)&Whi[(size_t)c*K + s*32 + jj*8];
      *(u8v*)&sWl[c*32 + jj*8] = *(const u8v*)&Wlo[(size_t)c*K + s*32 + jj*8];
    }
    __syncthreads();
    s8v ahi = *(const s8v*)&sAh[(wv*16 + lr)*32 + kg*8];
    s8v alo = hasLo ? *(const s8v*)&sAl[(wv*16 + lr)*32 + kg*8] : (s8v)(short)0;
    #pragma unroll
    for (int f = 0; f < 8; f++){
      s8v bhi = *(const s8v*)&sWh[(f*16 + lr)*32 + kg*8];
      s8v blo = *(const s8v*)&sWl[(f*16 + lr)*32 + kg*8];
      acc[f] = __builtin_amdgcn_mfma_f32_16x16x32_bf16(ahi, bhi, acc[f], 0, 0, 0);
      acc[f] = __builtin_amdgcn_mfma_f32_16x16x32_bf16(ahi, blo, acc[f], 0, 0, 0);
      if (hasLo)
        acc[f] = __builtin_amdgcn_mfma_f32_16x16x32_bf16(alo, bhi, acc[f], 0, 0, 0);
    }
  }

  if (MODE == 0){
    #pragma unroll
    for (int q = 0; q < 4; q++){
      int node = nbase + kg*4 + q;
      if (node >= N) continue;
      float s0 = 0.f, s1 = 0.f;
      #pragma unroll
      for (int k = 0; k < 4; k++){
        s0 += fmaxf(acc[2*k][q]   + bias[k*32 + lr],      0.f);
        s1 += fmaxf(acc[2*k+1][q] + bias[k*32 + 16 + lr], 0.f);
      }
      float v0 = 0.25f*s0, v1 = 0.25f*s1;
      out[(size_t)node*32 + lr]      = v0;
      out[(size_t)node*32 + 16 + lr] = v1;
      ushort_t h0 = bf16rne(v0), h1 = bf16rne(v1);
      ohi[(size_t)node*32 + lr]      = h0;
      ohi[(size_t)node*32 + 16 + lr] = h1;
      olo[(size_t)node*32 + lr]      = bf16rne(v0 - bf16f(h0));
      olo[(size_t)node*32 + 16 + lr] = bf16rne(v1 - bf16f(h1));
    }
  } else {
    #pragma unroll
    for (int q = 0; q < 4; q++){
      int node = nbase + kg*4 + q;
      if (node >= N) continue;
      #pragma unroll
      for (int f = 0; f < 8; f++){
        float v = fmaxf(acc[f][q] + bias[f*16 + lr], 0.f);
        ushort_t h = bf16rne(v);
        ohi[(size_t)node*128 + f*16 + lr] = h;
        olo[(size_t)node*128 + f*16 + lr] = bf16rne(v - bf16f(h));
      }
    }
  }
}

// ---------- head: relu(h@W3+b3)@W4+b4 ----------
__global__ void k_head(const float* __restrict__ h,
                       const float* __restrict__ W3, const float* __restrict__ b3,
                       const float* __restrict__ W4, const float* __restrict__ b4,
                       float* __restrict__ out, int N){
  __shared__ float sW3[32*16], sb3[16], sW4[16*2], sb4[2];
  int t = threadIdx.x;
  for (int i = t; i < 512; i += TPB) sW3[i] = W3[i];
  if (t < 16) sb3[t] = b3[t];
  if (t < 32) sW4[t] = W4[t];
  if (t < 2)  sb4[t] = b4[t];
  __syncthreads();
  int n = blockIdx.x*TPB + t;
  if (n >= N) return;
  float hin[32];
  #pragma unroll
  for (int j = 0; j < 32; j++) hin[j] = h[(size_t)n*32 + j];
  float m[16];
  #pragma unroll
  for (int o = 0; o < 16; o++){
    float a = sb3[o];
    #pragma unroll
    for (int j = 0; j < 32; j++) a += hin[j]*sW3[j*16 + o];
    m[o] = fmaxf(a, 0.f);
  }
  float o0 = sb4[0], o1 = sb4[1];
  #pragma unroll
  for (int j = 0; j < 16; j++){ o0 += m[j]*sW4[j*2]; o1 += m[j]*sW4[j*2+1]; }
  out[(size_t)n*2]     = o0;
  out[(size_t)n*2 + 1] = o1;
}

extern "C" void kernel_launch(void* const* d_in, const int* in_sizes, int n_in,
                              void* d_out, int out_size, void* d_ws, size_t ws_size,
                              hipStream_t stream){
  const float* x     = (const float*)d_in[0];
  const int*   ei    = (const int*)  d_in[1];
  const float* fc1_w = (const float*)d_in[2];
  const float* fc1_b = (const float*)d_in[3];
  const float* fc2_w = (const float*)d_in[4];
  const float* fc2_b = (const float*)d_in[5];
  const float* a_iw[4] = {(const float*)d_in[6],  (const float*)d_in[9],  (const float*)d_in[12], (const float*)d_in[15]};
  const float* a_rw[4] = {(const float*)d_in[7],  (const float*)d_in[10], (const float*)d_in[13], (const float*)d_in[16]};
  const float* a_b [4] = {(const float*)d_in[8],  (const float*)d_in[11], (const float*)d_in[14], (const float*)d_in[17]};
  const float* fc3_w = (const float*)d_in[18];
  const float* fc3_b = (const float*)d_in[19];
  const float* fc4_w = (const float*)d_in[20];
  const float* fc4_b = (const float*)d_in[21];

  const int N = in_sizes[0] / 4;
  const int E = in_sizes[1] / 2;
  const int* row = ei;
  const int* col = ei + E;
  const int NB = (N + 255) >> BKT_SH;
  const int chunk = (E + NBLK_A - 1) / NBLK_A;

  char* p = (char*)d_ws;
  auto alloc = [&](size_t bytes)->void*{
    void* q = (void*)p;
    p += (bytes + 255) & ~size_t(255);
    return q;
  };
  float*    dis    = (float*)   alloc((size_t)N*4);
  int*      cnt    = (int*)     alloc((size_t)N*4);
  int*      off    = (int*)     alloc((size_t)N*4);
  const int nb     = (N + 1023) / 1024;
  int*      bsums  = (int*)     alloc((size_t)nb*4);
  int*      esrc   = (int*)     alloc((size_t)E*4);
  int2*     binned = (int2*)    alloc((size_t)E*8);
  int*      hist   = (int*)     alloc((size_t)NB*NBLK_A*4);
  int*      btot   = (int*)     alloc((size_t)NB*4);
  int*      bbase  = (int*)     alloc((size_t)(NB+1)*4);
  ushort_t* mhi    = (ushort_t*)alloc((size_t)N*32*2);
  ushort_t* mlo    = (ushort_t*)alloc((size_t)N*32*2);
  ushort_t* h1hi   = (ushort_t*)alloc((size_t)N*128*2);
  ushort_t* h1lo   = (ushort_t*)alloc((size_t)N*128*2);
  ushort_t* agHhi  = (ushort_t*)alloc((size_t)N*128*2);
  ushort_t* agShi  = (ushort_t*)alloc((size_t)N*32*2);
  float*    h2f    = (float*)   alloc((size_t)N*32*4);
  ushort_t* h2hi   = (ushort_t*)alloc((size_t)N*32*2);
  ushort_t* h2lo   = (ushort_t*)alloc((size_t)N*32*2);
  float*    h3f    = (float*)   alloc((size_t)N*32*4);
  ushort_t* h3hi   = (ushort_t*)alloc((size_t)N*32*2);
  ushort_t* h3lo   = (ushort_t*)alloc((size_t)N*32*2);
  ushort_t* WFhi   = (ushort_t*)alloc((size_t)128*32*2);
  ushort_t* WFlo   = (ushort_t*)alloc((size_t)128*32*2);
  ushort_t* W1hi   = (ushort_t*)alloc((size_t)128*256*2);
  ushort_t* W1lo   = (ushort_t*)alloc((size_t)128*256*2);
  ushort_t* WAhi[4], *WAlo[4];
  WAhi[0] = W1hi; WAlo[0] = W1lo;
  for (int L = 1; L < 4; L++){
    WAhi[L] = (ushort_t*)alloc((size_t)128*64*2);
    WAlo[L] = (ushort_t*)alloc((size_t)128*64*2);
  }

  // ---- atomic-free bucketed CSR build ----
  k_hist   <<<NBLK_A, TPB, 0, stream>>>(col, E, NB, chunk, hist);
  k_bs1    <<<NB, TPB, 0, stream>>>(hist, btot);
  k_bs2    <<<1, 1, 0, stream>>>(btot, NB, bbase);
  k_bin    <<<NBLK_A, TPB, 0, stream>>>(row, col, E, NB, chunk, hist, bbase, binned);
  k_cnt    <<<NB, TPB, 0, stream>>>(binned, bbase, N, cnt);
  k_scan1  <<<nb, TPB, 0, stream>>>(cnt, N, off, bsums, dis);
  k_scan2  <<<1, 1, 0, stream>>>(bsums, nb);
  k_scan3  <<<(N+TPB-1)/TPB, TPB, 0, stream>>>(off, bsums, N);
  k_scatter<<<NB, TPB, 0, stream>>>(binned, bbase, off, N, esrc);

  // weight prep (tiny)
  k_wprep_fc  <<<(128*32+TPB-1)/TPB,   TPB, 0, stream>>>(fc2_w, 32, WFhi, WFlo);
  k_wprep_arma<<<(128*256+TPB-1)/TPB,  TPB, 0, stream>>>(a_iw[0], a_rw[0], 128, W1hi, W1lo);
  for (int L = 1; L < 4; L++)
    k_wprep_arma<<<(128*64+TPB-1)/TPB, TPB, 0, stream>>>(a_iw[L], a_rw[L], 32, WAhi[L], WAlo[L]);

  const int gm = (N + 63) / 64;
  k_fc1<<<((size_t)N*32+TPB-1)/TPB, TPB, 0, stream>>>(x, fc1_w, fc1_b, mhi, mlo, N);
  k_mfma<32,1,1,1><<<gm, TPB, 0, stream>>>(mhi, mlo, mhi, mlo, WFhi, WFlo, fc2_b,
                                           nullptr, h1hi, h1lo, N);

  // ARMA 1 (fin=128): bf16 gather (hi table, hi-only out), split-MFMA -> h2
  k_gatherb<128><<<(N+15)/16, TPB, 0, stream>>>((const unsigned*)h1hi, off, cnt, esrc, dis, agHhi, N);
  k_mfma<256,4,0,0><<<gm, TPB, 0, stream>>>(agHhi, nullptr, h1hi, h1lo, W1hi, W1lo, a_b[0],
                                            h2f, h2hi, h2lo, N);

  // ARMA 2..4 (fin=32): ping-pong (h2,*) <-> (h3,*)
  const ushort_t* hih = h2hi; const ushort_t* hil = h2lo;
  float* hof = h3f; ushort_t* hoh = h3hi; ushort_t* hol = h3lo;
  float* haltf = h2f;
  for (int L = 1; L < 4; L++){
    k_gatherb<32><<<(N+63)/64, TPB, 0, stream>>>((const unsigned*)hih, off, cnt, esrc, dis, agShi, N);
    k_mfma<64,1,0,0><<<gm, TPB, 0, stream>>>(agShi, nullptr, hih, hil, WAhi[L], WAlo[L], a_b[L],
                                             hof, hoh, hol, N);
    const ushort_t* th = hih; hih = hoh; hoh = (ushort_t*)th;
    const ushort_t* tl = hil; hil = hol; hol = (ushort_t*)tl;
    float* tf = haltf; haltf = hof; hof = tf;
  }

  // L2 wrote h3*, L3 wrote h2*, L4 wrote h3* -> final fp32 in h3f
  k_head<<<(N+TPB-1)/TPB, TPB, 0, stream>>>(h3f, fc3_w, fc3_b, fc4_w, fc4_b, (float*)d_out, N);
}